// Round 3
// baseline (4121.364 us; speedup 1.0000x reference)
//
#include <hip/hip_runtime.h>
#include <hip/hip_cooperative_groups.h>
#include <cstdint>
#include <cstddef>

#define B_  64
#define SE_ 128
#define T_  64
#define S_  1024
#define D_  1024
#define V_  32000

typedef __attribute__((ext_vector_type(8))) short bhalf8;
typedef __attribute__((ext_vector_type(4))) float floatx4;

__device__ __forceinline__ float sigmoidf_(float x){ return 1.0f/(1.0f+__expf(-x)); }

__device__ __forceinline__ ushort f2bf(float f){
  uint32_t u = __float_as_uint(f);
  uint32_t r = (u + 0x7fffu + ((u >> 16) & 1u)) >> 16;
  return (ushort)r;
}
__device__ __forceinline__ float bf2f(ushort h){ return __uint_as_float(((uint32_t)h) << 16); }

__device__ __forceinline__ void glds16(const ushort* g, ushort* l){
  __builtin_amdgcn_global_load_lds((const __attribute__((address_space(1))) void*)g,
                                   (__attribute__((address_space(3))) void*)l, 16, 0, 0);
}

__device__ __forceinline__ float waveRedSum(float v){
  #pragma unroll
  for (int off = 32; off; off >>= 1) v += __shfl_down(v, off, 64);
  return v;
}

// ---------------- attention path (fp32, small) ----------------

__global__ void k_attnvec(const float* __restrict__ ayi_w, const float* __restrict__ aw_w,
                          float* __restrict__ v){
  int wave = (blockIdx.x * blockDim.x + threadIdx.x) >> 6;
  int lane = threadIdx.x & 63;
  if (wave >= S_) return;
  const float* row = ayi_w + (size_t)wave * S_;
  float acc = 0.f;
  #pragma unroll 4
  for (int s = lane; s < S_; s += 64) acc += row[s] * aw_w[s];
  acc = waveRedSum(acc);
  if (lane == 0) v[wave] = acc;
}

__global__ void k_scores(const float* __restrict__ yts, const float* __restrict__ v,
                         float* __restrict__ scores){
  int wave = (blockIdx.x * blockDim.x + threadIdx.x) >> 6;
  int lane = threadIdx.x & 63;
  const float* row = yts + (size_t)wave * S_;
  float acc = 0.f;
  #pragma unroll 4
  for (int s = lane; s < S_; s += 64) acc += row[s] * v[s];
  acc = waveRedSum(acc);
  if (lane == 0) scores[wave] = acc;
}

__global__ void k_attn(const float* __restrict__ scores, float* __restrict__ attnw,
                       float* __restrict__ outAttn){
  int b = blockIdx.x;
  int e = threadIdx.x;
  __shared__ float sm[128];
  float x = scores[b*SE_ + e];
  sm[e] = x; __syncthreads();
  #pragma unroll
  for (int off = 64; off; off >>= 1){
    if (e < off) sm[e] = fmaxf(sm[e], sm[e+off]);
    __syncthreads();
  }
  float m = sm[0]; __syncthreads();
  float p = __expf(x - m);
  sm[e] = p; __syncthreads();
  #pragma unroll
  for (int off = 64; off; off >>= 1){
    if (e < off) sm[e] += sm[e+off];
    __syncthreads();
  }
  float a = p / sm[0];
  attnw[b*SE_ + e] = a;
  float* dst = outAttn + (size_t)b * T_ * SE_ + e;
  #pragma unroll 4
  for (int t = 0; t < T_; ++t) dst[t*SE_] = a;
}

__global__ void k_ctx(const float* __restrict__ yts, const float* __restrict__ attnw,
                      float* __restrict__ ctx){
  int idx = blockIdx.x * blockDim.x + threadIdx.x;
  int b = idx >> 10, s = idx & (S_-1);
  const float* base = yts + (size_t)b * SE_ * S_ + s;
  const float* a = attnw + b * SE_;
  float acc = 0.f;
  #pragma unroll 8
  for (int e = 0; e < SE_; ++e) acc += a[e] * base[(size_t)e * S_];
  ctx[idx] = acc;
}

// ---------------- conversion / packing ----------------

__global__ void k_transcvt(const float* __restrict__ src, ushort* __restrict__ dst,
                           int K, int N){
  __shared__ float t[32][33];
  int n0 = blockIdx.x * 32, k0 = blockIdx.y * 32;
  for (int r = threadIdx.y; r < 32; r += 8)
    t[r][threadIdx.x] = src[(size_t)(k0 + r) * N + n0 + threadIdx.x];
  __syncthreads();
  for (int r = threadIdx.y; r < 32; r += 8)
    dst[(size_t)(n0 + r) * K + k0 + threadIdx.x] = f2bf(t[threadIdx.x][r]);
}

__global__ void k_cvt(const float* __restrict__ src, ushort* __restrict__ dst, int n4){
  int i = blockIdx.x * blockDim.x + threadIdx.x;
  if (i >= n4) return;
  float4 v = ((const float4*)src)[i];
  ushort4 o; o.x = f2bf(v.x); o.y = f2bf(v.y); o.z = f2bf(v.z); o.w = f2bf(v.w);
  ((ushort4*)dst)[i] = o;
}

__global__ void k_gathercvt(const float* __restrict__ emb, const int* __restrict__ tgt,
                            ushort* __restrict__ Xb){
  int r = blockIdx.x;
  int token = tgt[((r & 63) << 6) + (r >> 6)];
  const float4* src = (const float4*)(emb + (size_t)token * D_);
  ushort* dst = Xb + (size_t)r * D_;
  int i = threadIdx.x;
  float4 v = src[i];
  ushort4 o; o.x = f2bf(v.x); o.y = f2bf(v.y); o.z = f2bf(v.z); o.w = f2bf(v.w);
  ((ushort4*)dst)[i] = o;
}

__global__ void k_packbias(const float* __restrict__ wb0, const float* __restrict__ wb1,
                           const float* __restrict__ wb2, const float* __restrict__ wb3,
                           const float* __restrict__ ub0, const float* __restrict__ ub1,
                           const float* __restrict__ ub2, const float* __restrict__ ub3,
                           float* __restrict__ dst){
  int col = blockIdx.x * blockDim.x + threadIdx.x;
  int g = col >> 10, s = col & 1023;
  const float* wb = (g==0) ? wb0 : (g==1) ? wb1 : (g==2) ? wb2 : wb3;
  const float* ub = (g==0) ? ub0 : (g==1) ? ub1 : (g==2) ? ub2 : ub3;
  dst[col] = wb[s] + ub[s];
}

// ---------------- bf16 MFMA GEMM (m97 structure + XCD-chunked swizzle) ----------------
// C[M][N] = A[M][K=1024] * BT[N][K=1024]^T (+ bias[N])
// OUT_MODE: 0 = f32, 1 = f32 with row remap (t*64+b -> b*64+t), 2 = bf16
// Requires gridDim.x*gridDim.y % 8 == 0.
template<int OUT_MODE>
__global__ __launch_bounds__(256) void k_mfma_gemm(
    const ushort* __restrict__ A, const ushort* __restrict__ BT,
    const float* __restrict__ bias, void* __restrict__ C, int M, int N)
{
  __shared__ ushort As[128*32];
  __shared__ ushort Bs[128*32];
  const int tid = threadIdx.x;
  const int lane = tid & 63, w = tid >> 6;
  // XCD-chunked swizzle: each XCD gets a contiguous run of row-stripes
  const int nwg = gridDim.x * gridDim.y;
  const int L = blockIdx.y * gridDim.x + blockIdx.x;
  const int logical = (L & 7) * (nwg >> 3) + (L >> 3);
  const int by = logical / gridDim.x;
  const int bx = logical - by * gridDim.x;
  const int m0 = by * 128, n0 = bx * 128;
  const int wr = (w >> 1) * 64, wc = (w & 1) * 64;

  const int cr = (lane >> 2);
  const int ck = (lane & 3) * 8;
  const ushort* gA0 = A  + (size_t)(m0 + (2*w)*16   + cr) * 1024 + ck;
  const ushort* gA1 = A  + (size_t)(m0 + (2*w+1)*16 + cr) * 1024 + ck;
  const ushort* gB0 = BT + (size_t)(n0 + (2*w)*16   + cr) * 1024 + ck;
  const ushort* gB1 = BT + (size_t)(n0 + (2*w+1)*16 + cr) * 1024 + ck;
  ushort* lA0 = As + (2*w)*512;   ushort* lA1 = As + (2*w+1)*512;
  ushort* lB0 = Bs + (2*w)*512;   ushort* lB1 = Bs + (2*w+1)*512;

  floatx4 acc[4][4] = {};

  for (int kt = 0; kt < 1024; kt += 32) {
    glds16(gA0 + kt, lA0); glds16(gA1 + kt, lA1);
    glds16(gB0 + kt, lB0); glds16(gB1 + kt, lB1);
    __syncthreads();
    bhalf8 a[4], b[4];
    #pragma unroll
    for (int f = 0; f < 4; ++f) {
      a[f] = *(const bhalf8*)&As[(wr + f*16 + (lane & 15)) * 32 + (lane >> 4) * 8];
      b[f] = *(const bhalf8*)&Bs[(wc + f*16 + (lane & 15)) * 32 + (lane >> 4) * 8];
    }
    #pragma unroll
    for (int i = 0; i < 4; ++i)
      #pragma unroll
      for (int j = 0; j < 4; ++j)
        acc[i][j] = __builtin_amdgcn_mfma_f32_16x16x32_bf16(a[i], b[j], acc[i][j], 0, 0, 0);
    __syncthreads();
  }

  const int crow = (lane >> 4) * 4, ccol = lane & 15;
  #pragma unroll
  for (int i = 0; i < 4; ++i) {
    #pragma unroll
    for (int j = 0; j < 4; ++j) {
      int row = m0 + wr + i*16 + crow;
      int col = n0 + wc + j*16 + ccol;
      float bv = bias ? bias[col] : 0.f;
      #pragma unroll
      for (int r = 0; r < 4; ++r) {
        float v = acc[i][j][r] + bv;
        if (OUT_MODE == 0) {
          ((float*)C)[(size_t)(row + r) * N + col] = v;
        } else if (OUT_MODE == 1) {
          int rr = row + r;
          ((float*)C)[(size_t)(((rr & 63) << 6) + (rr >> 6)) * N + col] = v;
        } else {
          ((ushort*)C)[(size_t)(row + r) * N + col] = f2bf(v);
        }
      }
    }
  }
}

// ---------------- cooperative persistent recurrence ----------------
// 128 blocks x 512 threads. Block j owns s-cols [j*8, j*8+8) across all 4 gates
// (32 local gate-cols, local col c = g*8+sp). W panel (64 KB) lives in LDS for all
// 64 steps, XOR-swizzled. Wave w = (kq=w>>1, nh=w&1): K-quarter kq, N-half nh.
// A-fragments read global->VGPR (st is L2-broadcast). One grid.sync per step.
__global__ __launch_bounds__(512) void k_recur(
    const ushort* __restrict__ WT, const ushort* __restrict__ preb,
    const float* __restrict__ ctx, ushort* __restrict__ Hst)
{
  extern __shared__ char smem[];
  float* gbuf = (float*)(smem + 65536);     // [4 kq][64 b][33] f32 = 33792 B
  const int tid  = threadIdx.x;
  const int lane = tid & 63;
  const int w    = tid >> 6;
  const int kq   = w >> 1;
  const int nh   = w & 1;
  const int j    = blockIdx.x;

  // persistent W panel -> LDS (swizzled: byte = c*2048 + ((k2) ^ ((c&7)<<4)))
  for (int it = tid; it < 4096; it += 512) {
    int c = it >> 7, chunk = it & 127;
    int g = c >> 3, sp = c & 7;
    const uint4 v = *(const uint4*)(WT + (((size_t)(g*1024 + j*8 + sp)) << 10) + chunk*8);
    *(uint4*)(smem + c*2048 + ((chunk*16) ^ ((c & 7) << 4))) = v;
  }

  const int cb  = tid >> 3, csp = tid & 7;   // this thread's pointwise cell
  const float ctxv = ctx[(cb << 10) + j*8 + csp];

  const int arow = lane & 15;
  const int kof  = (lane >> 4) << 3;
  const int bc   = (nh << 4) + (lane & 15);  // local gate-col 0..31
  const int bswz = (bc & 7) << 4;

  cooperative_groups::grid_group grid = cooperative_groups::this_grid();
  __syncthreads();

  for (int t = 0; t < 64; ++t) {
    const ushort* Hp = Hst + ((size_t)t << 16);
    // early pre loads for this thread's cell (4 gates)
    const ushort* prow = preb + (((size_t)(t*64 + cb)) << 12) + j*8 + csp;
    ushort pg0 = prow[0], pg1 = prow[1024], pg2 = prow[2048], pg3 = prow[3072];

    const ushort* Ab = Hp + kq*256 + kof;
    floatx4 acc[4] = {};
    bhalf8 af[2][4];
    #pragma unroll
    for (int i = 0; i < 4; ++i)
      af[0][i] = *(const bhalf8*)(Ab + ((size_t)(i*16 + arow) << 10));
    #pragma unroll
    for (int i = 0; i < 4; ++i)
      af[1][i] = *(const bhalf8*)(Ab + ((size_t)(i*16 + arow) << 10) + 32);
    #pragma unroll
    for (int ks = 0; ks < 8; ++ks) {
      int k2 = (kq*256 + ks*32 + kof) * 2;
      bhalf8 bf = *(const bhalf8*)(smem + bc*2048 + (k2 ^ bswz));
      #pragma unroll
      for (int i = 0; i < 4; ++i)
        acc[i] = __builtin_amdgcn_mfma_f32_16x16x32_bf16(af[ks & 1][i], bf, acc[i], 0, 0, 0);
      if (ks < 6) {
        #pragma unroll
        for (int i = 0; i < 4; ++i)
          af[ks & 1][i] = *(const bhalf8*)(Ab + ((size_t)(i*16 + arow) << 10) + (ks + 2)*32);
      }
    }
    __syncthreads();
    #pragma unroll
    for (int i = 0; i < 4; ++i) {
      int row = i*16 + ((lane >> 4) << 2);
      #pragma unroll
      for (int r = 0; r < 4; ++r)
        gbuf[kq*2112 + (row + r)*33 + bc] = acc[i][r];
    }
    __syncthreads();
    {
      float g0 = 0.f, g1 = 0.f, g2 = 0.f, g3 = 0.f;
      #pragma unroll
      for (int q = 0; q < 4; ++q) {
        const float* gb = gbuf + q*2112 + cb*33;
        g0 += gb[csp]; g1 += gb[8 + csp]; g2 += gb[16 + csp]; g3 += gb[24 + csp];
      }
      g0 += bf2f(pg0); g1 += bf2f(pg1); g2 += bf2f(pg2); g3 += bf2f(pg3);
      float ft = sigmoidf_(g0), it_ = sigmoidf_(g1), ot = sigmoidf_(g2);
      float cbar = tanhf(g3);
      float ct = ft * ctxv + it_ * cbar;
      Hst[((size_t)(t + 1) << 16) + (cb << 10) + j*8 + csp] = f2bf(ot * tanhf(ct));
    }
    __threadfence();
    grid.sync();
  }
}

// ---------------- single-pass row softmax over V=32000 (row staged in LDS) ----------------
__global__ __launch_bounds__(256) void k_softmaxV(float* __restrict__ out){
  extern __shared__ float rowbuf[];     // 32000 f32 = 128000 B
  int r = blockIdx.x;
  float4* p = (float4*)(out + (size_t)r * V_);
  float4* rb = (float4*)rowbuf;
  int tid = threadIdx.x;
  float m = -1e30f, ssum = 0.f;
  for (int i = tid; i < 8000; i += 256) {
    float4 v = p[i];
    rb[i] = v;
    float m4 = fmaxf(fmaxf(v.x, v.y), fmaxf(v.z, v.w));
    float mn = fmaxf(m, m4);
    ssum = ssum * __expf(m - mn)
         + __expf(v.x - mn) + __expf(v.y - mn) + __expf(v.z - mn) + __expf(v.w - mn);
    m = mn;
  }
  __shared__ float ms[256], ss[256];
  ms[tid] = m; ss[tid] = ssum; __syncthreads();
  #pragma unroll
  for (int off = 128; off; off >>= 1) {
    if (tid < off) {
      float m2 = fmaxf(ms[tid], ms[tid+off]);
      ss[tid] = ss[tid]*__expf(ms[tid]-m2) + ss[tid+off]*__expf(ms[tid+off]-m2);
      ms[tid] = m2;
    }
    __syncthreads();
  }
  float M = ms[0];
  float inv = 1.0f / ss[0];
  for (int i = tid; i < 8000; i += 256) {
    float4 v = rb[i];
    v.x = __expf(v.x - M) * inv; v.y = __expf(v.y - M) * inv;
    v.z = __expf(v.z - M) * inv; v.w = __expf(v.w - M) * inv;
    p[i] = v;
  }
}

// ---------------- host ----------------

extern "C" void kernel_launch(void* const* d_in, const int* in_sizes, int n_in,
                              void* d_out, int out_size, void* d_ws, size_t ws_size,
                              hipStream_t stream){
  const float* yts   = (const float*)d_in[0];
  const float* enc_h = (const float*)d_in[1];
  const int*   tgt   = (const int*)d_in[2];
  const float* emb   = (const float*)d_in[3];
  const float* ayi_w = (const float*)d_in[6];
  const float* aw_w  = (const float*)d_in[8];
  const float* wf_w = (const float*)d_in[10]; const float* wf_b = (const float*)d_in[11];
  const float* uf_w = (const float*)d_in[12]; const float* uf_b = (const float*)d_in[13];
  const float* wi_w = (const float*)d_in[14]; const float* wi_b = (const float*)d_in[15];
  const float* ui_w = (const float*)d_in[16]; const float* ui_b = (const float*)d_in[17];
  const float* wo_w = (const float*)d_in[18]; const float* wo_b = (const float*)d_in[19];
  const float* uo_w = (const float*)d_in[20]; const float* uo_b = (const float*)d_in[21];
  const float* wc_w = (const float*)d_in[22]; const float* wc_b = (const float*)d_in[23];
  const float* uc_w = (const float*)d_in[24]; const float* uc_b = (const float*)d_in[25];
  const float* xh_w = (const float*)d_in[26]; const float* xh_b = (const float*)d_in[27];
  const float* cls_w= (const float*)d_in[28]; const float* cls_b= (const float*)d_in[29];

  float* out = (float*)d_out;
  float* outAttn = out + (size_t)B_ * T_ * V_;

  char* wsb = (char*)d_ws;
  size_t off = 0;
  auto alloc = [&](size_t bytes)->char*{
    char* p = wsb + off; off += (bytes + 255) & ~(size_t)255; return p;
  };
  ushort* clsT  = (ushort*)alloc((size_t)V_ * 1024 * 2);
  ushort* xhT   = (ushort*)alloc((size_t)1024 * 1024 * 2);
  ushort* WcatT = (ushort*)alloc((size_t)4096 * 1024 * 2);
  ushort* UcatT = (ushort*)alloc((size_t)4096 * 1024 * 2);
  float*  biasU = (float*)alloc(4096 * 4);
  float*  vvec  = (float*)alloc(S_ * 4);
  float*  scores= (float*)alloc(B_ * SE_ * 4);
  float*  attnw = (float*)alloc(B_ * SE_ * 4);
  float*  ctx   = (float*)alloc(B_ * S_ * 4);
  ushort* Xb    = (ushort*)alloc((size_t)4096 * 1024 * 2);
  ushort* preb  = (ushort*)alloc((size_t)4096 * 4096 * 2);
  ushort* Hst   = (ushort*)alloc((size_t)65 * 64 * 1024 * 2);
  if (off > ws_size) return;
  ushort* Zb = Xb; // Xb dead after pre-GEMM; reuse for Z

  dim3 tb(32, 8);
  k_transcvt<<<dim3(V_/32, 32), tb, 0, stream>>>(cls_w, clsT, 1024, V_);
  k_transcvt<<<dim3(32, 32), tb, 0, stream>>>(xh_w, xhT, 1024, 1024);
  k_transcvt<<<dim3(32, 32), tb, 0, stream>>>(wf_w, WcatT + 0u*1048576u, 1024, 1024);
  k_transcvt<<<dim3(32, 32), tb, 0, stream>>>(wi_w, WcatT + 1u*1048576u, 1024, 1024);
  k_transcvt<<<dim3(32, 32), tb, 0, stream>>>(wo_w, WcatT + 2u*1048576u, 1024, 1024);
  k_transcvt<<<dim3(32, 32), tb, 0, stream>>>(wc_w, WcatT + 3u*1048576u, 1024, 1024);
  k_transcvt<<<dim3(32, 32), tb, 0, stream>>>(uf_w, UcatT + 0u*1048576u, 1024, 1024);
  k_transcvt<<<dim3(32, 32), tb, 0, stream>>>(ui_w, UcatT + 1u*1048576u, 1024, 1024);
  k_transcvt<<<dim3(32, 32), tb, 0, stream>>>(uo_w, UcatT + 2u*1048576u, 1024, 1024);
  k_transcvt<<<dim3(32, 32), tb, 0, stream>>>(uc_w, UcatT + 3u*1048576u, 1024, 1024);
  k_packbias<<<16, 256, 0, stream>>>(wf_b, wi_b, wo_b, wc_b, uf_b, ui_b, uo_b, uc_b, biasU);
  k_cvt<<<64, 256, 0, stream>>>(enc_h, Hst, 16384);
  k_gathercvt<<<4096, 256, 0, stream>>>(emb, tgt, Xb);

  k_attnvec<<<256, 256, 0, stream>>>(ayi_w, aw_w, vvec);
  k_scores<<<2048, 256, 0, stream>>>(yts, vvec, scores);
  k_attn<<<64, 128, 0, stream>>>(scores, attnw, outAttn);
  k_ctx<<<256, 256, 0, stream>>>(yts, attnw, ctx);

  // pre = X @ Ucat + biasU  -> bf16 [4096][4096]
  k_mfma_gemm<2><<<dim3(32, 32), 256, 0, stream>>>(Xb, UcatT, biasU, preb, 4096, 4096);

  // persistent cooperative recurrence: all 64 steps in one launch
  {
    void* args[] = { (void*)&WcatT, (void*)&preb, (void*)&ctx, (void*)&Hst };
    hipLaunchCooperativeKernel((void*)k_recur, dim3(128), dim3(512), args, 99328, stream);
  }

  // Z = H @ xh_w + xh_b  -> bf16 [4096][1024]
  k_mfma_gemm<2><<<dim3(8, 32), 256, 0, stream>>>(Hst + 65536, xhT, xh_b, Zb, 4096, 1024);
  // out = Z @ cls_w + cls_b (rows remapped t*64+b -> b*64+t), f32
  k_mfma_gemm<1><<<dim3(V_/128, 32), 256, 0, stream>>>(Zb, clsT, cls_b, out, 4096, V_);
  // single-pass softmax, row staged in LDS
  k_softmaxV<<<4096, 256, 128000, stream>>>(out);
}